// Round 1
// baseline (153.359 us; speedup 1.0000x reference)
//
#include <hip/hip_runtime.h>
#include <stdint.h>

#define N 8192
#define NLAB 81

// GAMMA = 0.5, ETA = 0.5 (module constants in the reference, not inputs)
__device__ __constant__ float d_GAMMA = 0.5f;
__device__ __constant__ float d_ETA   = 0.5f;

// ---------------------------------------------------------------------------
// Kernel 1: pack 0/1 label rows (81 ints) into 2x uint64 bitmasks per row.
// One wave per row; lane l supplies bit l (and l+64 for l<17) via __ballot.
// ---------------------------------------------------------------------------
__global__ void pack_labels(const int* __restrict__ img, const int* __restrict__ tex,
                            uint64_t* __restrict__ ibits, uint64_t* __restrict__ tbits) {
    int row  = (blockIdx.x * blockDim.x + threadIdx.x) >> 6;   // one wave per row
    int lane = threadIdx.x & 63;
    if (row >= N) return;

    const int* ri = img + (size_t)row * NLAB;
    const int* rt = tex + (size_t)row * NLAB;

    int v0 = ri[lane];                                   // lanes 0..63 (<81, safe)
    int v1 = (lane < NLAB - 64) ? ri[64 + lane] : 0;     // lanes 0..16 -> bits 64..80
    uint64_t b0 = __ballot(v0 != 0);
    uint64_t b1 = __ballot(v1 != 0);
    if (lane == 0) { ibits[(size_t)row * 2] = b0; ibits[(size_t)row * 2 + 1] = b1; }

    v0 = rt[lane];
    v1 = (lane < NLAB - 64) ? rt[64 + lane] : 0;
    b0 = __ballot(v0 != 0);
    b1 = __ballot(v1 != 0);
    if (lane == 0) { tbits[(size_t)row * 2] = b0; tbits[(size_t)row * 2 + 1] = b1; }
}

// ---------------------------------------------------------------------------
// Kernel 2: term2 (quantization) + term3 (balance): one thread per row.
//   contrib = GAMMA * sum_k((B-F)^2 + (B-G)^2) + ETA * (rowsum(F)^2 + rowsum(G)^2)
// ---------------------------------------------------------------------------
__global__ void row_terms(const float4* __restrict__ F4, const float4* __restrict__ G4,
                          const float4* __restrict__ B4, double* __restrict__ acc) {
    int r = blockIdx.x * blockDim.x + threadIdx.x;
    float q = 0.f, rf = 0.f, rg = 0.f;
#pragma unroll
    for (int k = 0; k < 4; ++k) {
        float4 f = F4[(size_t)r * 4 + k];
        float4 g = G4[(size_t)r * 4 + k];
        float4 b = B4[(size_t)r * 4 + k];
        float d;
        d = b.x - f.x; q = fmaf(d, d, q);
        d = b.y - f.y; q = fmaf(d, d, q);
        d = b.z - f.z; q = fmaf(d, d, q);
        d = b.w - f.w; q = fmaf(d, d, q);
        d = b.x - g.x; q = fmaf(d, d, q);
        d = b.y - g.y; q = fmaf(d, d, q);
        d = b.z - g.z; q = fmaf(d, d, q);
        d = b.w - g.w; q = fmaf(d, d, q);
        rf += f.x + f.y + f.z + f.w;
        rg += g.x + g.y + g.z + g.w;
    }
    float val = d_GAMMA * q + d_ETA * (rf * rf + rg * rg);
#pragma unroll
    for (int off = 32; off; off >>= 1) val += __shfl_down(val, off, 64);
    if ((threadIdx.x & 63) == 0) atomicAdd(acc, (double)val);
}

// ---------------------------------------------------------------------------
// Kernel 3: main pair loop.
//   local += softplus(0.5*theta) - (sim ? theta : 0)
// Block: 256 threads, each owns MI=4 i-rows (F rows in registers).
// Block tile: 1024 i-rows x TJ=128 t-cols; G rows + tex bitmasks staged in LDS,
// read at a block-uniform address each iteration (broadcast, conflict-free).
// ---------------------------------------------------------------------------
#define NTH 256
#define MI  4
#define TJ  128

__global__ __launch_bounds__(NTH) void pair_kernel(
        const float4* __restrict__ F4, const float4* __restrict__ G4,
        const uint64_t* __restrict__ ibits, const uint64_t* __restrict__ tbits,
        double* __restrict__ acc) {
    __shared__ float4   sG[TJ * 4];     // 8 KB: 128 G rows (16 floats each)
    __shared__ uint64_t sT[TJ * 2];     // 2 KB: tex bitmasks
    __shared__ float    wsum[NTH / 64];

    const int tid = threadIdx.x;
    const int i0  = blockIdx.x * (NTH * MI);
    const int t0  = blockIdx.y * TJ;

    // stage G tile + tex bitmasks (coalesced)
    for (int idx = tid; idx < TJ * 4; idx += NTH) sG[idx] = G4[(size_t)t0 * 4 + idx];
    for (int idx = tid; idx < TJ * 2; idx += NTH) sT[idx] = tbits[(size_t)t0 * 2 + idx];

    // this thread's F rows + img bitmasks into registers
    float4   f[MI][4];
    uint64_t ib0[MI], ib1[MI];
#pragma unroll
    for (int m = 0; m < MI; ++m) {
        int i = i0 + tid + m * NTH;
#pragma unroll
        for (int k = 0; k < 4; ++k) f[m][k] = F4[(size_t)i * 4 + k];
        ib0[m] = ibits[(size_t)i * 2];
        ib1[m] = ibits[(size_t)i * 2 + 1];
    }
    __syncthreads();

    float local = 0.f;
    for (int t = 0; t < TJ; ++t) {
        float4 g0 = sG[t * 4 + 0];
        float4 g1 = sG[t * 4 + 1];
        float4 g2 = sG[t * 4 + 2];
        float4 g3 = sG[t * 4 + 3];
        uint64_t tb0 = sT[t * 2], tb1 = sT[t * 2 + 1];
#pragma unroll
        for (int m = 0; m < MI; ++m) {
            float th = f[m][0].x * g0.x;
            th = fmaf(f[m][0].y, g0.y, th);
            th = fmaf(f[m][0].z, g0.z, th);
            th = fmaf(f[m][0].w, g0.w, th);
            th = fmaf(f[m][1].x, g1.x, th);
            th = fmaf(f[m][1].y, g1.y, th);
            th = fmaf(f[m][1].z, g1.z, th);
            th = fmaf(f[m][1].w, g1.w, th);
            th = fmaf(f[m][2].x, g2.x, th);
            th = fmaf(f[m][2].y, g2.y, th);
            th = fmaf(f[m][2].z, g2.z, th);
            th = fmaf(f[m][2].w, g2.w, th);
            th = fmaf(f[m][3].x, g3.x, th);
            th = fmaf(f[m][3].y, g3.y, th);
            th = fmaf(f[m][3].z, g3.z, th);
            th = fmaf(f[m][3].w, g3.w, th);

            bool sim = (((ib0[m] & tb0) | (ib1[m] & tb1)) != 0ull);

            // numerically stable softplus(x), x = theta/2
            float x  = 0.5f * th;
            float ax = fabsf(x);
            float sp = fmaxf(x, 0.f) + __logf(1.f + __expf(-ax));

            local += sp - (sim ? th : 0.f);
        }
    }

    // wave reduce, then block reduce, one double atomic per block
#pragma unroll
    for (int off = 32; off; off >>= 1) local += __shfl_down(local, off, 64);
    if ((tid & 63) == 0) wsum[tid >> 6] = local;
    __syncthreads();
    if (tid == 0) {
        float s = wsum[0] + wsum[1] + wsum[2] + wsum[3];
        atomicAdd(acc, (double)s);
    }
}

// ---------------------------------------------------------------------------
__global__ void finalize(const double* __restrict__ acc, float* __restrict__ out) {
    out[0] = (float)acc[0];
}

extern "C" void kernel_launch(void* const* d_in, const int* in_sizes, int n_in,
                              void* d_out, int out_size, void* d_ws, size_t ws_size,
                              hipStream_t stream) {
    const float* F   = (const float*)d_in[0];
    const float* G   = (const float*)d_in[1];
    const float* B   = (const float*)d_in[2];
    const int*   img = (const int*)d_in[3];
    const int*   tex = (const int*)d_in[4];

    char*     ws    = (char*)d_ws;
    double*   acc   = (double*)ws;                                   // 8 B (pad to 64)
    uint64_t* ibits = (uint64_t*)(ws + 64);                          // 128 KB
    uint64_t* tbits = (uint64_t*)(ws + 64 + (size_t)N * 2 * sizeof(uint64_t));

    hipMemsetAsync(acc, 0, 64, stream);

    pack_labels<<<N / 4, 256, 0, stream>>>(img, tex, ibits, tbits);

    row_terms<<<N / 256, 256, 0, stream>>>((const float4*)F, (const float4*)G,
                                           (const float4*)B, acc);

    dim3 grid(N / (NTH * MI), N / TJ);   // 8 x 64 = 512 blocks
    pair_kernel<<<grid, NTH, 0, stream>>>((const float4*)F, (const float4*)G,
                                          ibits, tbits, acc);

    finalize<<<1, 1, 0, stream>>>(acc, (float*)d_out);
}

// Round 2
// 110.067 us; speedup vs baseline: 1.3933x; 1.3933x over previous
//
#include <hip/hip_runtime.h>
#include <stdint.h>

#define N 8192
#define NLAB 81

typedef short bf16x8 __attribute__((ext_vector_type(8)));
typedef float f32x4  __attribute__((ext_vector_type(4)));

// fp32 -> bf16 (RNE), no NaN handling needed (inputs are finite gaussians)
__device__ __forceinline__ ushort f2bf(float x) {
    uint32_t u = __float_as_uint(x);
    u += 0x7fffu + ((u >> 16) & 1u);
    return (ushort)(u >> 16);
}

// ---------------------------------------------------------------------------
// Kernel 1: pack 0/1 label rows (81 ints) into uint4 (2x u64) bitmasks.
// One wave per row via __ballot.
// ---------------------------------------------------------------------------
__global__ void pack_labels(const int* __restrict__ img, const int* __restrict__ tex,
                            uint4* __restrict__ ibits, uint4* __restrict__ tbits) {
    int row  = (blockIdx.x * blockDim.x + threadIdx.x) >> 6;
    int lane = threadIdx.x & 63;
    if (row >= N) return;

    const int* ri = img + (size_t)row * NLAB;
    const int* rt = tex + (size_t)row * NLAB;

    uint64_t b0 = __ballot(ri[lane] != 0);
    uint64_t b1 = __ballot(lane < NLAB - 64 ? (ri[64 + lane] != 0) : false);
    if (lane == 0) ibits[row] = make_uint4((uint32_t)b0, (uint32_t)(b0 >> 32),
                                           (uint32_t)b1, (uint32_t)(b1 >> 32));

    b0 = __ballot(rt[lane] != 0);
    b1 = __ballot(lane < NLAB - 64 ? (rt[64 + lane] != 0) : false);
    if (lane == 0) tbits[row] = make_uint4((uint32_t)b0, (uint32_t)(b0 >> 32),
                                           (uint32_t)b1, (uint32_t)(b1 >> 32));
}

// ---------------------------------------------------------------------------
// Kernel 2: term2 (quantization) + term3 (balance), one thread per row.
// Writes one double partial per block (slots 2048..2079). No atomics.
// ---------------------------------------------------------------------------
__global__ void row_terms(const float4* __restrict__ F4, const float4* __restrict__ G4,
                          const float4* __restrict__ B4, double* __restrict__ partials) {
    __shared__ float wsum[4];
    int r = blockIdx.x * blockDim.x + threadIdx.x;
    float q = 0.f, rf = 0.f, rg = 0.f;
#pragma unroll
    for (int k = 0; k < 4; ++k) {
        float4 f = F4[(size_t)r * 4 + k];
        float4 g = G4[(size_t)r * 4 + k];
        float4 b = B4[(size_t)r * 4 + k];
        float d;
        d = b.x - f.x; q = fmaf(d, d, q);
        d = b.y - f.y; q = fmaf(d, d, q);
        d = b.z - f.z; q = fmaf(d, d, q);
        d = b.w - f.w; q = fmaf(d, d, q);
        d = b.x - g.x; q = fmaf(d, d, q);
        d = b.y - g.y; q = fmaf(d, d, q);
        d = b.z - g.z; q = fmaf(d, d, q);
        d = b.w - g.w; q = fmaf(d, d, q);
        rf += f.x + f.y + f.z + f.w;
        rg += g.x + g.y + g.z + g.w;
    }
    float val = 0.5f * q + 0.5f * (rf * rf + rg * rg);   // GAMMA = ETA = 0.5
#pragma unroll
    for (int off = 32; off; off >>= 1) val += __shfl_down(val, off, 64);
    if ((threadIdx.x & 63) == 0) wsum[threadIdx.x >> 6] = val;
    __syncthreads();
    if (threadIdx.x == 0)
        partials[2048 + blockIdx.x] = (double)(wsum[0] + wsum[1] + wsum[2] + wsum[3]);
}

// ---------------------------------------------------------------------------
// Kernel 3: pair loop via bf16 MFMA 16x16x32 (K zero-padded 16->32).
// Wave = fixed 32-row i-strip (2 A-frags + 8 img masks in regs, loaded once),
// sweeping a 256-col t-chunk staged in LDS (bf16 G rows + tex masks).
// contribution = 0.5*max(th,0) + ln2*log2(1+exp2(-|th|*log2e/2)) - sim*th
// Grid: (64 i-blocks of 128 rows) x (32 t-chunks of 256 cols) = 2048 blocks.
// ---------------------------------------------------------------------------
__global__ __launch_bounds__(256) void pair_kernel(
        const float* __restrict__ F, const float* __restrict__ G,
        const uint4* __restrict__ ibits, const uint4* __restrict__ tbits,
        double* __restrict__ partials) {
    __shared__ ushort sGb[256 * 16];   // 8 KB: t-chunk of G in bf16
    __shared__ uint4  sTb[256];        // 4 KB: t-chunk tex masks
    __shared__ float  wsum[4];

    const int tid     = threadIdx.x;
    const int wid     = tid >> 6;
    const int lane    = tid & 63;
    const int col     = lane & 15;        // MFMA n / C-col
    const int quad    = lane >> 4;        // 0..3
    const int koff    = (quad & 1) * 8;   // element offset inside K=16
    const int i0      = (blockIdx.x * 4 + wid) * 32;
    const int t_begin = blockIdx.y * 256;

    // ---- stage G chunk (bf16) + tex masks into LDS ----
    for (int idx = tid; idx < 256 * 4; idx += 256) {
        int r = idx >> 2, c4 = idx & 3;
        float4 g = *(const float4*)(G + (size_t)(t_begin + r) * 16 + c4 * 4);
        uint2 w;
        w.x = (uint32_t)f2bf(g.x) | ((uint32_t)f2bf(g.y) << 16);
        w.y = (uint32_t)f2bf(g.z) | ((uint32_t)f2bf(g.w) << 16);
        *(uint2*)(sGb + r * 16 + c4 * 4) = w;
    }
    sTb[tid] = tbits[t_begin + tid];

    // ---- A-frags (rows i0+col and i0+16+col, k = koff..koff+7) ----
    bf16x8 a0, a1;
    {
        const float4* p0 = (const float4*)(F + (size_t)(i0 + col) * 16 + koff);
        const float4* p1 = (const float4*)(F + (size_t)(i0 + 16 + col) * 16 + koff);
        float4 x0 = p0[0], y0 = p0[1];
        float4 x1 = p1[0], y1 = p1[1];
        a0[0] = (short)f2bf(x0.x); a0[1] = (short)f2bf(x0.y);
        a0[2] = (short)f2bf(x0.z); a0[3] = (short)f2bf(x0.w);
        a0[4] = (short)f2bf(y0.x); a0[5] = (short)f2bf(y0.y);
        a0[6] = (short)f2bf(y0.z); a0[7] = (short)f2bf(y0.w);
        a1[0] = (short)f2bf(x1.x); a1[1] = (short)f2bf(x1.y);
        a1[2] = (short)f2bf(x1.z); a1[3] = (short)f2bf(x1.w);
        a1[4] = (short)f2bf(y1.x); a1[5] = (short)f2bf(y1.y);
        a1[6] = (short)f2bf(y1.z); a1[7] = (short)f2bf(y1.w);
        if (quad >= 2) {   // zero-pad K 16->32: quads 2,3 of A are zero
            bf16x8 z = {0, 0, 0, 0, 0, 0, 0, 0};
            a0 = z; a1 = z;
        }
    }

    // ---- img masks for the 8 (s, reg) C-rows this lane sees: row = s*16+quad*4+r
    uint4 ib[8];
#pragma unroll
    for (int s = 0; s < 2; ++s)
#pragma unroll
        for (int r = 0; r < 4; ++r)
            ib[s * 4 + r] = ibits[i0 + s * 16 + quad * 4 + r];

    __syncthreads();

    const f32x4 zero4 = {0.f, 0.f, 0.f, 0.f};
    float sMax = 0.f, sLog = 0.f, sSim = 0.f;

#pragma unroll 2
    for (int ts = 0; ts < 16; ++ts) {
        const int tl = ts * 16;
        bf16x8 b  = *(const bf16x8*)(sGb + (tl + col) * 16 + koff);
        uint4  tb = sTb[tl + col];

        f32x4 c0 = __builtin_amdgcn_mfma_f32_16x16x32_bf16(a0, b, zero4, 0, 0, 0);
        f32x4 c1 = __builtin_amdgcn_mfma_f32_16x16x32_bf16(a1, b, zero4, 0, 0, 0);

#pragma unroll
        for (int s = 0; s < 2; ++s) {
#pragma unroll
            for (int r = 0; r < 4; ++r) {
                float th = s ? c1[r] : c0[r];
                uint4 m4 = ib[s * 4 + r];
                uint32_t mm = (m4.x & tb.x) | (m4.y & tb.y) |
                              (m4.z & tb.z) | (m4.w & tb.w);
                // softplus(th/2) in log2 domain: exp2/log2 are single HW ops
                float e  = __builtin_amdgcn_exp2f(fabsf(th) * -0.7213475204f); // -log2(e)/2
                float lg = __builtin_amdgcn_logf(1.0f + e);                    // log2
                sLog += lg;
                sMax += fmaxf(th, 0.f);
                sSim += (mm != 0u) ? th : 0.f;
            }
        }
    }

    float local = fmaf(0.69314718056f, sLog, fmaf(0.5f, sMax, -sSim));
#pragma unroll
    for (int off = 32; off; off >>= 1) local += __shfl_down(local, off, 64);
    if (lane == 0) wsum[wid] = local;
    __syncthreads();
    if (tid == 0)
        partials[blockIdx.y * 64 + blockIdx.x] =
            (double)(wsum[0] + wsum[1] + wsum[2] + wsum[3]);
}

// ---------------------------------------------------------------------------
// Kernel 4: sum 2080 per-block partials -> scalar output.
// ---------------------------------------------------------------------------
__global__ void finalize(const double* __restrict__ p, float* __restrict__ out) {
    __shared__ double sd[4];
    double t = 0.0;
    for (int i = threadIdx.x; i < 2080; i += 256) t += p[i];
#pragma unroll
    for (int off = 32; off; off >>= 1) t += __shfl_down(t, off, 64);
    if ((threadIdx.x & 63) == 0) sd[threadIdx.x >> 6] = t;
    __syncthreads();
    if (threadIdx.x == 0) out[0] = (float)(sd[0] + sd[1] + sd[2] + sd[3]);
}

extern "C" void kernel_launch(void* const* d_in, const int* in_sizes, int n_in,
                              void* d_out, int out_size, void* d_ws, size_t ws_size,
                              hipStream_t stream) {
    const float* F   = (const float*)d_in[0];
    const float* G   = (const float*)d_in[1];
    const float* B   = (const float*)d_in[2];
    const int*   img = (const int*)d_in[3];
    const int*   tex = (const int*)d_in[4];

    char*   ws       = (char*)d_ws;
    double* partials = (double*)ws;                               // 2080 doubles
    uint4*  ibits    = (uint4*)(ws + 17 * 1024);                  // 128 KB
    uint4*  tbits    = (uint4*)(ws + 17 * 1024 + 131072);         // 128 KB

    pack_labels<<<N / 4, 256, 0, stream>>>(img, tex, ibits, tbits);

    row_terms<<<N / 256, 256, 0, stream>>>((const float4*)F, (const float4*)G,
                                           (const float4*)B, partials);

    dim3 grid(64, 32);   // 64 i-blocks x 32 t-chunks
    pair_kernel<<<grid, 256, 0, stream>>>(F, G, ibits, tbits, partials);

    finalize<<<1, 256, 0, stream>>>(partials, (float*)d_out);
}